// Round 1
// baseline (206.948 us; speedup 1.0000x reference)
//
#include <hip/hip_runtime.h>
#include <math.h>

// Problem constants
#define BB 16          // batch
#define TT 50          // targets per batch
#define GG 64          // grid 64x64
#define NLOC 3         // local anchors
#define NCLS 80
#define NATTR 85       // 5 + 80
#define NCH 255        // 3*85
#define NCELLS (BB*NLOC*GG*GG)   // 196608
#define CLAMP_BCE 27.631021f     // -log(1e-12)

// anchors / 8 (scale_w = 512/64 = 8, a0 = 6)
__constant__ float c_AW[9] = {1.25f, 2.0f, 4.125f, 3.75f, 7.75f, 7.375f, 14.5f, 19.5f, 46.625f};
__constant__ float c_AH[9] = {1.625f, 3.75f, 2.875f, 7.625f, 5.625f, 14.875f, 11.25f, 24.75f, 40.75f};

struct TG {
    int   valid, hit, gi, gj, local, cls, best;
    float gx, gy, gw, gh, il0, il1, il2;
};

__device__ __forceinline__ float softplus_c(float z) {
    // min( log(1+e^z), -log(EPS) )  == -log(1 - clip(sigmoid(z))) to fp32 noise
    float sp = fmaxf(z, 0.f) + log1pf(expf(-fabsf(z)));
    return fminf(sp, CLAMP_BCE);
}
__device__ __forceinline__ float sigmoidf_(float z) { return 1.f / (1.f + expf(-z)); }

__device__ __forceinline__ TG compute_tgt(const float* __restrict__ gt, int b, int i) {
    TG r;
    const float* g = gt + (b * TT + i) * 5;
    float x = g[0], y = g[1], w = g[2], h = g[3], c = g[4];
    r.valid = (x + y + w + h + c) > 0.f;
    r.gx = x * 64.f; r.gy = y * 64.f; r.gw = w * 64.f; r.gh = h * 64.f;
    r.gi = (int)r.gy;   // row from gy
    r.gj = (int)r.gx;   // col from gx
    r.cls = (int)c;
    float bi = -1.f; int ba = 0;
    float il[3] = {0.f, 0.f, 0.f};
    #pragma unroll
    for (int a = 0; a < 9; a++) {
        float aw = c_AW[a], ah = c_AH[a];
        float inter = fminf(r.gw, aw) * fminf(r.gh, ah);
        float uni   = r.gw * r.gh + aw * ah - inter;
        float iou   = inter / (uni + 1e-16f);
        if (iou > bi) { bi = iou; ba = a; }   // strict > : first max (jnp.argmax)
        if (a >= 6) il[a - 6] = iou;
    }
    r.best = ba; r.il0 = il[0]; r.il1 = il[1]; r.il2 = il[2];
    r.local = ba - 6;
    r.hit = r.valid && (r.local >= 0) && (r.local < NLOC);
    return r;
}

// ws accumulators (floats at ws+0): [0]=S_all [1]=Sx [2]=Sy [3]=Sw [4]=Sh
// [5]=S_obj [6]=S_cls [7]=S_maskadj [8]=S_sub ; ints at ws+64: [0]=n_obj [1]=n_zeroed
__global__ void k_prep(const float* __restrict__ bb, const float* __restrict__ gt,
                       float* __restrict__ accf, int* __restrict__ acci) {
    __shared__ unsigned bitmap[NCELLS / 32];   // 6144 u32 = 24 KB
    __shared__ int cells[BB * TT];
    __shared__ float s_sub;
    __shared__ int s_nobj, s_nzero;
    int tid = threadIdx.x;
    for (int i = tid; i < NCELLS / 32; i += 256) bitmap[i] = 0u;
    if (tid == 0) { s_sub = 0.f; s_nobj = 0; s_nzero = 0; }
    if (tid < 32) ((unsigned*)accf)[tid] = 0u;   // zero all accumulators (poisoned ws)
    __syncthreads();

    for (int t = tid; t < BB * TT; t += 256) {
        int b = t / TT, i = t - b * TT;
        TG r = compute_tgt(gt, b, i);
        cells[t] = r.hit ? (((b * NLOC + r.local) * GG + r.gi) * GG + r.gj) : -1;
        if (r.valid) {
            float il[3] = {r.il0, r.il1, r.il2};
            #pragma unroll
            for (int a = 0; a < NLOC; a++) {
                if (il[a] > 0.5f) {
                    int cell = ((b * NLOC + a) * GG + r.gi) * GG + r.gj;
                    atomicOr(&bitmap[cell >> 5], 1u << (cell & 31));
                }
            }
        }
    }
    __syncthreads();

    // n_obj = distinct mask cells = count of "last-writer" winners
    int nobj = 0;
    for (int t = tid; t < BB * TT; t += 256) {
        int c = cells[t];
        if (c < 0) continue;
        int b = t / TT, i = t - b * TT;
        bool win = true;
        for (int j = i + 1; j < TT; j++)
            if (cells[b * TT + j] == c) { win = false; break; }
        if (win) nobj++;
    }

    // distinct noobj-zeroed cells: count + subtract their softplus(z_conf)
    int nz = 0; float sub = 0.f;
    for (int wI = tid; wI < NCELLS / 32; wI += 256) {
        unsigned u = bitmap[wI];
        nz += __popc(u);
        while (u) {
            int bit = __ffs(u) - 1;
            u &= u - 1;
            int cell  = wI * 32 + bit;
            int plane = cell >> 12, off = cell & 4095;  // plane = b*3+a
            int b = plane / 3, a = plane - b * 3;
            float z = bb[((b * NCH + a * NATTR + 4) << 12) + off];
            sub += softplus_c(z);
        }
    }
    atomicAdd(&s_nobj, nobj);
    atomicAdd(&s_nzero, nz);
    atomicAdd(&s_sub, sub);
    __syncthreads();
    if (tid == 0) {
        accf[8] = s_sub;
        acci[0] = s_nobj;
        acci[1] = s_nzero;
    }
}

// Dense sum of softplus(z_conf) over all B*3*64*64 cells (y=0 assumption)
__global__ void k_conf_sum(const float* __restrict__ bb, float* __restrict__ accf) {
    __shared__ float s;
    int tid = threadIdx.x;
    if (tid == 0) s = 0.f;
    __syncthreads();
    int idx   = blockIdx.x * 256 + tid;          // 0 .. 196607
    int plane = idx >> 12, off = idx & 4095;
    int b = plane / 3, a = plane - b * 3;
    float v = softplus_c(bb[((b * NCH + a * NATTR + 4) << 12) + off]);
    #pragma unroll
    for (int o = 32; o > 0; o >>= 1) v += __shfl_down(v, o);
    if ((tid & 63) == 0) atomicAdd(&s, v);
    __syncthreads();
    if (tid == 0) atomicAdd(&accf[0], s);
}

// Per-target: winner determination + bbox/obj/cls contributions
__global__ void k_obj(const float* __restrict__ bb, const float* __restrict__ gt,
                      float* __restrict__ accf) {
    __shared__ TG R;
    __shared__ int notwin, zeroed;
    __shared__ unsigned clsmask[3];
    __shared__ float s_cls;
    int t = blockIdx.x;
    int b = t / TT, i = t - b * TT;
    int tid = threadIdx.x;
    if (tid == 0) {
        R = compute_tgt(gt, b, i);
        notwin = 0; zeroed = 0;
        clsmask[0] = clsmask[1] = clsmask[2] = 0u;
        s_cls = 0.f;
    }
    __syncthreads();
    if (!R.hit) return;
    int cell = ((b * NLOC + R.local) * GG + R.gi) * GG + R.gj;

    if (tid < TT) {
        int j = tid;
        TG q = compute_tgt(gt, b, j);
        int cj = q.hit ? (((b * NLOC + q.local) * GG + q.gi) * GG + q.gj) : -1;
        if (cj == cell) {
            if (j > i) notwin = 1;                       // last scatter update wins
            atomicOr(&clsmask[q.cls >> 5], 1u << (q.cls & 31));  // t_cls .max union
        }
        float ilr = (R.local == 0) ? q.il0 : (R.local == 1) ? q.il1 : q.il2;
        if (q.valid && q.gi == R.gi && q.gj == R.gj && ilr > 0.5f) zeroed = 1;
    }
    __syncthreads();
    if (notwin) return;

    float tx = R.gx - (float)R.gj;
    float ty = R.gy - (float)R.gi;
    float tw = logf(R.gw / c_AW[R.best] + 1e-16f);
    float th = logf(R.gh / c_AH[R.best] + 1e-16f);
    int base = ((b * NCH + R.local * NATTR) << 12) + (R.gi << 6) + R.gj;

    if (tid < NCLS) {
        unsigned y = (clsmask[tid >> 5] >> (tid & 31)) & 1u;
        float z = bb[base + ((5 + tid) << 12)];
        atomicAdd(&s_cls, y ? softplus_c(-z) : softplus_c(z));
    } else if (tid < NCLS + 5) {
        int attr = tid - NCLS;
        float z = bb[base + (attr << 12)];
        if (attr == 0)      { float d = sigmoidf_(z) - tx; atomicAdd(&accf[1], d * d); }
        else if (attr == 1) { float d = sigmoidf_(z) - ty; atomicAdd(&accf[2], d * d); }
        else if (attr == 2) { float d = z - tw;            atomicAdd(&accf[3], d * d); }
        else if (attr == 3) { float d = z - th;            atomicAdd(&accf[4], d * d); }
        else {
            float b1 = softplus_c(-z);                    // bce(p, 1)
            atomicAdd(&accf[5], b1);                      // loss_obj numerator
            if (!zeroed) {                                // mask=1 & noobj=1 correction
                float b0 = softplus_c(z);
                atomicAdd(&accf[7], b1 - b0);
            }
        }
    }
    __syncthreads();
    if (tid == 0) atomicAdd(&accf[6], s_cls);
}

__global__ void k_final(const float* __restrict__ accf, const int* __restrict__ acci,
                        float* __restrict__ out) {
    float S_all = accf[0], Sx = accf[1], Sy = accf[2], Sw = accf[3], Sh = accf[4];
    float So = accf[5], Sc = accf[6], Sadj = accf[7], Ssub = accf[8];
    float nobj = fmaxf((float)acci[0], 1.f);
    float nno  = fmaxf((float)(NCELLS - acci[1]), 1.f);
    float bbox = 5.f * (Sx + Sy + Sw + Sh) / nobj;
    float objl = 1.0f * So / nobj + 0.5f * (S_all - Ssub + Sadj) / nno;
    float clsl = 1.0f * Sc / (nobj * (float)NCLS);
    out[0] = bbox + objl + clsl;
    out[1] = bbox;
    out[2] = objl;
    out[3] = clsl;
}

extern "C" void kernel_launch(void* const* d_in, const int* in_sizes, int n_in,
                              void* d_out, int out_size, void* d_ws, size_t ws_size,
                              hipStream_t stream) {
    const float* bb = (const float*)d_in[0];   // backbone_out [16,255,64,64]
    const float* gt = (const float*)d_in[1];   // gt_targets   [16,50,5]
    float* accf = (float*)d_ws;
    int*   acci = (int*)d_ws + 16;             // byte offset 64
    float* out  = (float*)d_out;

    k_prep    <<<1,                256, 0, stream>>>(bb, gt, accf, acci);
    k_conf_sum<<<NCELLS / 256,     256, 0, stream>>>(bb, accf);
    k_obj     <<<BB * TT,          128, 0, stream>>>(bb, gt, accf);
    k_final   <<<1,                1,   0, stream>>>(accf, acci, out);
}

// Round 2
// 118.256 us; speedup vs baseline: 1.7500x; 1.7500x over previous
//
#include <hip/hip_runtime.h>
#include <math.h>

// Problem constants
#define BB 16          // batch
#define TT 50          // targets per batch
#define GG 64          // grid 64x64
#define NLOC 3
#define NCLS 80
#define NATTR 85
#define NCH 255
#define NCELLS (BB*NLOC*GG*GG)   // 196608
#define NB_DENSE (NCELLS/256)    // 768
#define NB_TGT (BB*TT)           // 800
#define NB_TOTAL (NB_DENSE + NB_TGT)
#define NP 12                    // partial-vector stride (floats) per block
#define CLAMP_BCE 27.631021f     // -log(1e-12)

// anchors / 8 (scale_w = 512/64 = 8, a0 = 6)
__constant__ float c_AW[9] = {1.25f, 2.0f, 4.125f, 3.75f, 7.75f, 7.375f, 14.5f, 19.5f, 46.625f};
__constant__ float c_AH[9] = {1.625f, 3.75f, 2.875f, 7.625f, 5.625f, 14.875f, 11.25f, 24.75f, 40.75f};

struct TG {
    int   valid, hit, gi, gj, local, cls, best;
    float gx, gy, gw, gh, il0, il1, il2;
};

__device__ __forceinline__ float softplus_c(float z) {
    float sp = fmaxf(z, 0.f) + log1pf(expf(-fabsf(z)));
    return fminf(sp, CLAMP_BCE);
}
__device__ __forceinline__ float sigmoidf_(float z) { return 1.f / (1.f + expf(-z)); }

__device__ __forceinline__ TG compute_tgt(const float* __restrict__ gt, int b, int i) {
    TG r;
    const float* g = gt + (b * TT + i) * 5;
    float x = g[0], y = g[1], w = g[2], h = g[3], c = g[4];
    r.valid = (x + y + w + h + c) > 0.f;
    r.gx = x * 64.f; r.gy = y * 64.f; r.gw = w * 64.f; r.gh = h * 64.f;
    r.gi = (int)r.gy;
    r.gj = (int)r.gx;
    r.cls = (int)c;
    float bi = -1.f; int ba = 0;
    float il[3] = {0.f, 0.f, 0.f};
    #pragma unroll
    for (int a = 0; a < 9; a++) {
        float aw = c_AW[a], ah = c_AH[a];
        float inter = fminf(r.gw, aw) * fminf(r.gh, ah);
        float uni   = r.gw * r.gh + aw * ah - inter;
        float iou   = inter / (uni + 1e-16f);
        if (iou > bi) { bi = iou; ba = a; }   // strict > : first max (jnp.argmax)
        if (a >= 6) il[a - 6] = iou;
    }
    r.best = ba; r.il0 = il[0]; r.il1 = il[1]; r.il2 = il[2];
    r.local = ba - 6;
    r.hit = r.valid && (r.local >= 0) && (r.local < NLOC);
    return r;
}

// Partial layout per block (NP floats):
// [0]=S_all [1]=Sx [2]=Sy [3]=Sw [4]=Sh [5]=S_obj [6]=S_cls [7]=S_maskadj [8]=n_obj
__global__ void __launch_bounds__(256) k_main(const float* __restrict__ bb,
                                              const float* __restrict__ gt,
                                              float* __restrict__ partial) {
    int blk = blockIdx.x;
    int tid = threadIdx.x;

    if (blk < NB_DENSE) {
        // ---- dense conf softplus sum over 256 cells ----
        __shared__ float s;
        if (tid == 0) s = 0.f;
        __syncthreads();
        int idx   = blk * 256 + tid;
        int plane = idx >> 12, off = idx & 4095;
        int b = plane / 3, a = plane - b * 3;
        float v = softplus_c(bb[((b * NCH + a * NATTR + 4) << 12) + off]);
        #pragma unroll
        for (int o = 32; o > 0; o >>= 1) v += __shfl_down(v, o);
        if ((tid & 63) == 0) atomicAdd(&s, v);   // LDS atomic, 4 waves
        __syncthreads();
        if (tid < NP) partial[blk * NP + tid] = (tid == 0) ? s : 0.f;
        return;
    }

    // ---- per-target block ----
    __shared__ TG tg[TT];
    __shared__ float acc[NP];
    __shared__ unsigned clsmask[3];
    __shared__ int notwin, zeroed;
    int t = blk - NB_DENSE;
    int b = t / TT, i = t - b * TT;

    if (tid < NP) acc[tid] = 0.f;
    if (tid < 3) clsmask[tid] = 0u;
    if (tid == 0) { notwin = 0; zeroed = 0; }
    if (tid < TT) tg[tid] = compute_tgt(gt, b, tid);
    __syncthreads();

    TG R = tg[i];
    int cell = R.hit ? (((b * NLOC + R.local) * GG + R.gi) * GG + R.gj) : -1;

    if (R.hit && tid < TT) {
        TG q = tg[tid];
        int cj = q.hit ? (((b * NLOC + q.local) * GG + q.gi) * GG + q.gj) : -1;
        if (cj == cell) {
            if (tid > i) notwin = 1;                              // last scatter wins
            atomicOr(&clsmask[q.cls >> 5], 1u << (q.cls & 31));   // t_cls .max union
        }
        float ilr = (R.local == 0) ? q.il0 : (R.local == 1) ? q.il1 : q.il2;
        if (q.valid && q.gi == R.gi && q.gj == R.gj && ilr > 0.5f) zeroed = 1;
    }
    __syncthreads();

    if (R.hit && !notwin) {
        int base = ((b * NCH + R.local * NATTR) << 12) + (R.gi << 6) + R.gj;
        if (tid < NCLS) {
            unsigned y = (clsmask[tid >> 5] >> (tid & 31)) & 1u;
            float z = bb[base + ((5 + tid) << 12)];
            atomicAdd(&acc[6], y ? softplus_c(-z) : softplus_c(z));
        } else if (tid < NCLS + 5) {
            int attr = tid - NCLS;
            float z = bb[base + (attr << 12)];
            if (attr == 0)      { float tx = R.gx - (float)R.gj; float d = sigmoidf_(z) - tx; acc[1] = d * d; }
            else if (attr == 1) { float ty = R.gy - (float)R.gi; float d = sigmoidf_(z) - ty; acc[2] = d * d; }
            else if (attr == 2) { float tw = logf(R.gw / c_AW[R.best] + 1e-16f); float d = z - tw; acc[3] = d * d; }
            else if (attr == 3) { float th = logf(R.gh / c_AH[R.best] + 1e-16f); float d = z - th; acc[4] = d * d; }
            else {
                float b1 = softplus_c(-z);          // bce(p, 1)
                acc[5] = b1;
                if (!zeroed) acc[7] = b1 - softplus_c(z);   // mask=1 & noobj=1 correction
                acc[8] = 1.f;                        // n_obj (winner)
            }
        }
    }
    __syncthreads();
    if (tid < NP) partial[blk * NP + tid] = acc[tid];
}

__global__ void __launch_bounds__(256) k_final(const float* __restrict__ bb,
                                               const float* __restrict__ gt,
                                               const float* __restrict__ partial,
                                               float* __restrict__ out) {
    __shared__ unsigned bitmap[NCELLS / 32];   // 24 KB
    __shared__ float red[NP];
    __shared__ float s_sub;
    __shared__ int s_nz;
    int tid = threadIdx.x;

    for (int i = tid; i < NCELLS / 32; i += 256) bitmap[i] = 0u;
    if (tid < NP) red[tid] = 0.f;
    if (tid == 0) { s_sub = 0.f; s_nz = 0; }
    __syncthreads();

    // reduce partials: each thread accumulates 9 components over strided blocks
    float s[9];
    #pragma unroll
    for (int c = 0; c < 9; c++) s[c] = 0.f;
    for (int idx = tid; idx < NB_TOTAL; idx += 256) {
        const float* p = partial + idx * NP;
        #pragma unroll
        for (int c = 0; c < 9; c++) s[c] += p[c];
    }
    #pragma unroll
    for (int c = 0; c < 9; c++) {
        float v = s[c];
        #pragma unroll
        for (int o = 32; o > 0; o >>= 1) v += __shfl_down(v, o);
        if ((tid & 63) == 0) atomicAdd(&red[c], v);
    }

    // bitmap of noobj-zeroed cells
    for (int t = tid; t < BB * TT; t += 256) {
        int b = t / TT, i = t - b * TT;
        TG r = compute_tgt(gt, b, i);
        if (r.valid) {
            float il[3] = {r.il0, r.il1, r.il2};
            #pragma unroll
            for (int a = 0; a < NLOC; a++) {
                if (il[a] > 0.5f) {
                    int cell = ((b * NLOC + a) * GG + r.gi) * GG + r.gj;
                    atomicOr(&bitmap[cell >> 5], 1u << (cell & 31));
                }
            }
        }
    }
    __syncthreads();

    // dedup: count zeroed cells + subtract their softplus(z_conf)
    int nz = 0; float sub = 0.f;
    for (int wI = tid; wI < NCELLS / 32; wI += 256) {
        unsigned u = bitmap[wI];
        nz += __popc(u);
        while (u) {
            int bit = __ffs(u) - 1;
            u &= u - 1;
            int cell  = wI * 32 + bit;
            int plane = cell >> 12, off = cell & 4095;
            int b = plane / 3, a = plane - b * 3;
            sub += softplus_c(bb[((b * NCH + a * NATTR + 4) << 12) + off]);
        }
    }
    {
        float v = sub;
        int n = nz;
        #pragma unroll
        for (int o = 32; o > 0; o >>= 1) { v += __shfl_down(v, o); n += __shfl_down(n, o); }
        if ((tid & 63) == 0) { atomicAdd(&s_sub, v); atomicAdd(&s_nz, n); }
    }
    __syncthreads();

    if (tid == 0) {
        float nobj = fmaxf(red[8], 1.f);
        float nno  = fmaxf((float)NCELLS - (float)s_nz, 1.f);
        float bbox = 5.f * (red[1] + red[2] + red[3] + red[4]) / nobj;
        float objl = red[5] / nobj + 0.5f * (red[0] - s_sub + red[7]) / nno;
        float clsl = red[6] / (nobj * (float)NCLS);
        out[0] = bbox + objl + clsl;
        out[1] = bbox;
        out[2] = objl;
        out[3] = clsl;
    }
}

extern "C" void kernel_launch(void* const* d_in, const int* in_sizes, int n_in,
                              void* d_out, int out_size, void* d_ws, size_t ws_size,
                              hipStream_t stream) {
    const float* bb = (const float*)d_in[0];   // backbone_out [16,255,64,64]
    const float* gt = (const float*)d_in[1];   // gt_targets   [16,50,5]
    float* partial = (float*)d_ws;             // NB_TOTAL * NP floats = ~75 KB
    float* out = (float*)d_out;

    k_main <<<NB_TOTAL, 256, 0, stream>>>(bb, gt, partial);
    k_final<<<1,        256, 0, stream>>>(bb, gt, partial, out);
}

// Round 3
// 103.092 us; speedup vs baseline: 2.0074x; 1.1471x over previous
//
#include <hip/hip_runtime.h>
#include <math.h>

#define BB 16
#define TT 50
#define GG 64
#define NLOC 3
#define NCLS 80
#define NATTR 85
#define NCH 255
#define NCELLS (BB*NLOC*GG*GG)   // 196608
#define NB_DENSE 192             // 192 blocks * 128 thr * 2 float4 = 196608 floats
#define NB_TGT (BB*TT)           // 800
#define NB_TOTAL (NB_DENSE + NB_TGT)  // 992
#define NP 12
#define CLAMP_BCE 27.631021f     // -log(1e-12)

// anchors / 8 (scale_w = 512/64 = 8, a0 = 6)
__constant__ float c_AW[9] = {1.25f, 2.0f, 4.125f, 3.75f, 7.75f, 7.375f, 14.5f, 19.5f, 46.625f};
__constant__ float c_AH[9] = {1.625f, 3.75f, 2.875f, 7.625f, 5.625f, 14.875f, 11.25f, 24.75f, 40.75f};

struct TG {
    int   valid, hit, gi, gj, local, cls, best;
    float gx, gy, gw, gh, il0, il1, il2;
};

__device__ __forceinline__ float softplus_c(float z) {
    float sp = fmaxf(z, 0.f) + log1pf(expf(-fabsf(z)));
    return fminf(sp, CLAMP_BCE);
}
__device__ __forceinline__ float sigmoidf_(float z) { return 1.f / (1.f + expf(-z)); }

__device__ __forceinline__ TG compute_tgt(const float* __restrict__ gt, int b, int i) {
    TG r;
    const float* g = gt + (b * TT + i) * 5;
    float x = g[0], y = g[1], w = g[2], h = g[3], c = g[4];
    r.valid = (x + y + w + h + c) > 0.f;
    r.gx = x * 64.f; r.gy = y * 64.f; r.gw = w * 64.f; r.gh = h * 64.f;
    r.gi = (int)r.gy;
    r.gj = (int)r.gx;
    r.cls = (int)c;
    float bi = -1.f; int ba = 0;
    float il[3] = {0.f, 0.f, 0.f};
    #pragma unroll
    for (int a = 0; a < 9; a++) {
        float aw = c_AW[a], ah = c_AH[a];
        float inter = fminf(r.gw, aw) * fminf(r.gh, ah);
        float uni   = r.gw * r.gh + aw * ah - inter;
        float iou   = inter / (uni + 1e-16f);
        if (iou > bi) { bi = iou; ba = a; }   // strict > : first max (jnp.argmax)
        if (a >= 6) il[a - 6] = iou;
    }
    r.best = ba; r.il0 = il[0]; r.il1 = il[1]; r.il2 = il[2];
    r.local = ba - 6;
    r.hit = r.valid && (r.local >= 0) && (r.local < NLOC);
    return r;
}

// Partial layout per block (NP floats):
// [0]=S_all [1]=Sx [2]=Sy [3]=Sw [4]=Sh [5]=S_obj [6]=S_cls [7]=S_maskadj
// [8]=n_obj [9]=S_sub [10]=n_zeroed [11]=unused
__global__ void __launch_bounds__(128) k_main(const float* __restrict__ bb,
                                              const float* __restrict__ gt,
                                              float* __restrict__ partial) {
    int blk = blockIdx.x;
    int tid = threadIdx.x;

    if (blk < NB_DENSE) {
        // ---- dense conf softplus sum: 2 float4 per thread ----
        const float4* bb4 = (const float4*)bb;
        float v = 0.f;
        #pragma unroll
        for (int r = 0; r < 2; r++) {
            int idx4  = blk * 256 + r * 128 + tid;   // [0, 49152)
            int plane = idx4 >> 10;                  // 1024 float4 per conf plane
            int off4  = idx4 & 1023;
            int b = plane / 3, a = plane - b * 3;
            float4 q = bb4[((b * NCH + a * NATTR + 4) << 10) + off4];
            v += softplus_c(q.x) + softplus_c(q.y) + softplus_c(q.z) + softplus_c(q.w);
        }
        #pragma unroll
        for (int o = 32; o > 0; o >>= 1) v += __shfl_down(v, o);
        __shared__ float sred[2];
        if ((tid & 63) == 0) sred[tid >> 6] = v;
        __syncthreads();
        if (tid < NP) partial[blk * NP + tid] = (tid == 0) ? (sred[0] + sred[1]) : 0.f;
        return;
    }

    // ---- per-target block ----
    __shared__ TG tg[TT];
    __shared__ float acc[NP];
    __shared__ unsigned clsmask[3];
    __shared__ int notwin, zeroed;
    int t = blk - NB_DENSE;
    int b = t / TT, i = t - b * TT;

    if (tid < NP) acc[tid] = 0.f;
    if (tid < 3) clsmask[tid] = 0u;
    if (tid == 0) { notwin = 0; zeroed = 0; }
    if (tid < TT) tg[tid] = compute_tgt(gt, b, tid);
    __syncthreads();

    TG R = tg[i];

    // -- zeroed-cell ownership: anchor a = tid (0..2). Cell (b,a,gi,gj) is
    //    claimed by every valid target with il[a]>0.5; the EARLIEST claimer
    //    owns it (counts it once and subtracts its softplus(z_conf)).
    if (tid < 3 && R.valid) {
        float ila = (tid == 0) ? R.il0 : (tid == 1) ? R.il1 : R.il2;
        if (ila > 0.5f) {
            bool own = true;
            for (int j = 0; j < i; j++) {
                TG q = tg[j];
                float ilq = (tid == 0) ? q.il0 : (tid == 1) ? q.il1 : q.il2;
                if (q.valid && q.gi == R.gi && q.gj == R.gj && ilq > 0.5f) { own = false; break; }
            }
            if (own) {
                float z = bb[((b * NCH + tid * NATTR + 4) << 12) + (R.gi << 6) + R.gj];
                atomicAdd(&acc[9], softplus_c(z));
                atomicAdd(&acc[10], 1.f);
            }
        }
    }

    int cell = R.hit ? ((R.local << 12) + (R.gi << 6) + R.gj) : -1;
    if (R.hit && tid < TT) {
        TG q = tg[tid];
        int cj = q.hit ? ((q.local << 12) + (q.gi << 6) + q.gj) : -1;
        if (cj == cell) {
            if (tid > i) notwin = 1;                              // last scatter wins
            atomicOr(&clsmask[q.cls >> 5], 1u << (q.cls & 31));   // t_cls .max union
        }
        float ilr = (R.local == 0) ? q.il0 : (R.local == 1) ? q.il1 : q.il2;
        if (q.valid && q.gi == R.gi && q.gj == R.gj && ilr > 0.5f) zeroed = 1;
    }
    __syncthreads();

    if (R.hit && !notwin) {
        int base = ((b * NCH + R.local * NATTR) << 12) + (R.gi << 6) + R.gj;
        if (tid < NCLS) {
            unsigned y = (clsmask[tid >> 5] >> (tid & 31)) & 1u;
            float z = bb[base + ((5 + tid) << 12)];
            atomicAdd(&acc[6], y ? softplus_c(-z) : softplus_c(z));
        } else if (tid < NCLS + 5) {
            int attr = tid - NCLS;
            float z = bb[base + (attr << 12)];
            if (attr == 0)      { float tx = R.gx - (float)R.gj; float d = sigmoidf_(z) - tx; acc[1] = d * d; }
            else if (attr == 1) { float ty = R.gy - (float)R.gi; float d = sigmoidf_(z) - ty; acc[2] = d * d; }
            else if (attr == 2) { float tw = logf(R.gw / c_AW[R.best] + 1e-16f); float d = z - tw; acc[3] = d * d; }
            else if (attr == 3) { float th = logf(R.gh / c_AH[R.best] + 1e-16f); float d = z - th; acc[4] = d * d; }
            else {
                float b1 = softplus_c(-z);                      // bce(p, 1)
                acc[5] = b1;
                if (!zeroed) acc[7] = b1 - softplus_c(z);       // mask=1 & noobj=1
                acc[8] = 1.f;                                   // n_obj
            }
        }
    }
    __syncthreads();
    if (tid < NP) partial[blk * NP + tid] = acc[tid];
}

__global__ void __launch_bounds__(256) k_final(const float* __restrict__ partial,
                                               float* __restrict__ out) {
    __shared__ float red[NP];
    int tid = threadIdx.x;
    if (tid < NP) red[tid] = 0.f;
    __syncthreads();

    float s[11];
    #pragma unroll
    for (int c = 0; c < 11; c++) s[c] = 0.f;
    for (int idx = tid; idx < NB_TOTAL; idx += 256) {
        const float* p = partial + idx * NP;
        #pragma unroll
        for (int c = 0; c < 11; c++) s[c] += p[c];
    }
    #pragma unroll
    for (int c = 0; c < 11; c++) {
        float v = s[c];
        #pragma unroll
        for (int o = 32; o > 0; o >>= 1) v += __shfl_down(v, o);
        if ((tid & 63) == 0) atomicAdd(&red[c], v);
    }
    __syncthreads();

    if (tid == 0) {
        float nobj = fmaxf(red[8], 1.f);
        float nno  = fmaxf((float)NCELLS - red[10], 1.f);
        float bbox = 5.f * (red[1] + red[2] + red[3] + red[4]) / nobj;
        float objl = red[5] / nobj + 0.5f * (red[0] - red[9] + red[7]) / nno;
        float clsl = red[6] / (nobj * (float)NCLS);
        out[0] = bbox + objl + clsl;
        out[1] = bbox;
        out[2] = objl;
        out[3] = clsl;
    }
}

extern "C" void kernel_launch(void* const* d_in, const int* in_sizes, int n_in,
                              void* d_out, int out_size, void* d_ws, size_t ws_size,
                              hipStream_t stream) {
    const float* bb = (const float*)d_in[0];   // backbone_out [16,255,64,64]
    const float* gt = (const float*)d_in[1];   // gt_targets   [16,50,5]
    float* partial = (float*)d_ws;             // NB_TOTAL * NP floats ≈ 47.6 KB
    float* out = (float*)d_out;

    k_main <<<NB_TOTAL, 128, 0, stream>>>(bb, gt, partial);
    k_final<<<1,        256, 0, stream>>>(partial, out);
}